// Round 2
// baseline (374.555 us; speedup 1.0000x reference)
//
#include <hip/hip_runtime.h>

// Problem constants (match reference)
#define Bc 32
#define Lc 4096
#define Dc 512
#define Mc 256
#define EPSc 1e-9f

// op types
#define OP_IDENTITY 2
#define OP_CANCEL_START 3
#define OP_CANCEL_END 4
#define OP_STAR_ZERO 5

#define NBLOCKS 2048   // B*M / 4 waves per block

__device__ __forceinline__ float wave_allreduce_sum(float v) {
    #pragma unroll
    for (int m = 1; m < 64; m <<= 1) v += __shfl_xor(v, m, 64);
    return v;
}

// ws layout (32 B, zeroed by kernel_launch's memset):
//   float g_sums[3]; int g_cnts[3]; unsigned int ticket; unsigned int pad;
__global__ __launch_bounds__(256) void ops_kernel(
    const float* __restrict__ states,
    const int* __restrict__ op_types,
    const int* __restrict__ op_before_pos,
    const int* __restrict__ op_after_pos,
    const int* __restrict__ n_ops,
    float* __restrict__ g_sums,
    int* __restrict__ g_cnts,
    unsigned int* __restrict__ ticket,
    float* __restrict__ out)
{
    __shared__ float s_sums[3];
    __shared__ int   s_cnts[3];
    __shared__ int   s_last;
    if (threadIdx.x < 3) { s_sums[threadIdx.x] = 0.0f; s_cnts[threadIdx.x] = 0; }
    __syncthreads();

    const int wave = threadIdx.x >> 6;
    const int lane = threadIdx.x & 63;
    const int gid  = blockIdx.x * 4 + wave;      // [0, B*M)
    const int b    = gid >> 8;                   // M = 256
    const int m    = gid & (Mc - 1);

    const int n  = n_ops[b];
    const int t  = op_types[b * Mc + m];
    const int bp = op_before_pos[b * Mc + m];
    const int ap = op_after_pos[b * Mc + m];

    const bool in_n   = m < n;
    const bool pos_ok = (bp >= 0) & (bp < Lc) & (ap >= 0) & (ap < Lc);
    const bool valid  = in_n && pos_ok;

    const bool id_mask  = valid && (t == OP_IDENTITY);
    const bool col_mask = valid && (t == OP_STAR_ZERO);

    bool cancel_mask = false;
    int  apn_c = 0;
    if (valid && t == OP_CANCEL_START) {
        const int ot_next = (m + 1 < Mc) ? op_types[b * Mc + m + 1] : -1;
        const int ap_next = (m + 1 < Mc) ? op_after_pos[b * Mc + m + 1] : Lc;
        cancel_mask = ((m + 1) < n) && (ot_next == OP_CANCEL_END) && (ap_next < Lc);
        apn_c = min(max(ap_next, 0), Lc - 1);
    }

    if (id_mask || col_mask || cancel_mask) {
        const size_t baseB = (size_t)b * Lc * Dc;

        // before-row needed by every branch; pos_ok guarantees bp in range
        const float4* pbv = (const float4*)(states + baseB + (size_t)bp * Dc);
        const float4 bef0 = pbv[lane];
        const float4 bef1 = pbv[lane + 64];

        if (id_mask || col_mask) {
            const float4* pav = (const float4*)(states + baseB + (size_t)ap * Dc);
            const float4 aft0 = pav[lane];
            const float4 aft1 = pav[lane + 64];

            if (id_mask) {
                float acc = 0.0f, d;
                d = aft0.x - bef0.x; acc += d * d;
                d = aft0.y - bef0.y; acc += d * d;
                d = aft0.z - bef0.z; acc += d * d;
                d = aft0.w - bef0.w; acc += d * d;
                d = aft1.x - bef1.x; acc += d * d;
                d = aft1.y - bef1.y; acc += d * d;
                d = aft1.z - bef1.z; acc += d * d;
                d = aft1.w - bef1.w; acc += d * d;
                float mse = wave_allreduce_sum(acc) * (1.0f / (float)Dc);
                if (lane == 0) { atomicAdd(&s_sums[0], mse); atomicAdd(&s_cnts[0], 1); }
            } else {
                // collapse: relu(ent_after - ent_before + 0.5)
                float ea[8], eb[8];
                ea[0] = aft0.x * aft0.x; ea[1] = aft0.y * aft0.y;
                ea[2] = aft0.z * aft0.z; ea[3] = aft0.w * aft0.w;
                ea[4] = aft1.x * aft1.x; ea[5] = aft1.y * aft1.y;
                ea[6] = aft1.z * aft1.z; ea[7] = aft1.w * aft1.w;
                eb[0] = bef0.x * bef0.x; eb[1] = bef0.y * bef0.y;
                eb[2] = bef0.z * bef0.z; eb[3] = bef0.w * bef0.w;
                eb[4] = bef1.x * bef1.x; eb[5] = bef1.y * bef1.y;
                eb[6] = bef1.z * bef1.z; eb[7] = bef1.w * bef1.w;

                float Sa = 0.0f, Sb = 0.0f;
                #pragma unroll
                for (int i = 0; i < 8; ++i) { Sa += ea[i]; Sb += eb[i]; }
                Sa = wave_allreduce_sum(Sa);
                Sb = wave_allreduce_sum(Sb);

                const float inva = 1.0f / (Sa + EPSc);
                const float invb = 1.0f / (Sb + EPSc);
                float ha = 0.0f, hb = 0.0f;
                #pragma unroll
                for (int i = 0; i < 8; ++i) {
                    float pa = ea[i] * inva;
                    float pb = eb[i] * invb;
                    ha += pa * __log2f(pa + EPSc);
                    hb += pb * __log2f(pb + EPSc);
                }
                float ent_a = -wave_allreduce_sum(ha);
                float ent_b = -wave_allreduce_sum(hb);
                float term = fmaxf(ent_a - ent_b + 0.5f, 0.0f);
                if (lane == 0) { atomicAdd(&s_sums[2], term); atomicAdd(&s_cnts[2], 1); }
            }
        }

        if (cancel_mask) {
            const float4* pnv = (const float4*)(states + baseB + (size_t)apn_c * Dc);
            const float4 pr0 = pnv[lane];
            const float4 pr1 = pnv[lane + 64];
            float acc = 0.0f, d;
            d = pr0.x - bef0.x; acc += d * d;
            d = pr0.y - bef0.y; acc += d * d;
            d = pr0.z - bef0.z; acc += d * d;
            d = pr0.w - bef0.w; acc += d * d;
            d = pr1.x - bef1.x; acc += d * d;
            d = pr1.y - bef1.y; acc += d * d;
            d = pr1.z - bef1.z; acc += d * d;
            d = pr1.w - bef1.w; acc += d * d;
            float mse = wave_allreduce_sum(acc) * (1.0f / (float)Dc);
            if (lane == 0) { atomicAdd(&s_sums[1], mse); atomicAdd(&s_cnts[1], 1); }
        }
    }

    __syncthreads();

    // flush block partials to device-scope accumulators
    if (threadIdx.x < 3) {
        if (s_cnts[threadIdx.x] > 0) {
            atomicAdd(&g_sums[threadIdx.x], s_sums[threadIdx.x]);
            atomicAdd(&g_cnts[threadIdx.x], s_cnts[threadIdx.x]);
        }
        __threadfence();   // make flush visible before ticket increment
    }
    __syncthreads();

    if (threadIdx.x == 0) {
        unsigned int tk = atomicAdd(ticket, 1u);
        s_last = (tk == NBLOCKS - 1) ? 1 : 0;
    }
    __syncthreads();

    if (s_last && threadIdx.x == 0) {
        // coherent reads via device-scope RMW (per-XCD L2s are not coherent)
        float sid = atomicAdd(&g_sums[0], 0.0f);
        float sca = atomicAdd(&g_sums[1], 0.0f);
        float sco = atomicAdd(&g_sums[2], 0.0f);
        int cid = atomicAdd(&g_cnts[0], 0);
        int cca = atomicAdd(&g_cnts[1], 0);
        int cco = atomicAdd(&g_cnts[2], 0);
        float id = sid / fmaxf((float)cid, 1.0f);
        float ca = sca / fmaxf((float)cca, 1.0f);
        float co = sco / fmaxf((float)cco, 1.0f);
        out[0] = id + ca + 0.5f * co;   // IDENTITY_W=CANCEL_W=1, COLLAPSE_W=0.5
        out[1] = id;
        out[2] = ca;
        out[3] = co;
    }
}

extern "C" void kernel_launch(void* const* d_in, const int* in_sizes, int n_in,
                              void* d_out, int out_size, void* d_ws, size_t ws_size,
                              hipStream_t stream) {
    const float* states    = (const float*)d_in[0];
    const int*   op_types  = (const int*)d_in[1];
    const int*   op_before = (const int*)d_in[2];
    const int*   op_after  = (const int*)d_in[3];
    const int*   n_ops     = (const int*)d_in[4];
    float* out = (float*)d_out;

    float*        g_sums = (float*)d_ws;
    int*          g_cnts = (int*)((char*)d_ws + 3 * sizeof(float));
    unsigned int* ticket = (unsigned int*)((char*)d_ws + 6 * sizeof(int));

    // d_ws is re-poisoned to 0xAA before every timed launch — zero the 32 B we use.
    hipMemsetAsync(d_ws, 0, 32, stream);

    // one wave per (b, m): B*M = 8192 waves, 4 waves/block -> 2048 blocks
    ops_kernel<<<NBLOCKS, 256, 0, stream>>>(
        states, op_types, op_before, op_after, n_ops, g_sums, g_cnts, ticket, out);
}

// Round 3
// 322.797 us; speedup vs baseline: 1.1603x; 1.1603x over previous
//
#include <hip/hip_runtime.h>

// Problem constants (match reference)
#define Bc 32
#define Lc 4096
#define Dc 512
#define Mc 256
#define EPSc 1e-9f

// op types
#define OP_IDENTITY 2
#define OP_CANCEL_START 3
#define OP_CANCEL_END 4
#define OP_STAR_ZERO 5

__device__ __forceinline__ float wave_allreduce_sum(float v) {
    #pragma unroll
    for (int m = 1; m < 64; m <<= 1) v += __shfl_xor(v, m, 64);
    return v;
}

// One wave (64 lanes) per (b, m) op. Block = 256 threads = 4 waves.
// ws layout (24 B, zeroed by kernel_launch's memset): float g_sums[3]; int g_cnts[3];
__global__ __launch_bounds__(256) void ops_kernel(
    const float* __restrict__ states,
    const int* __restrict__ op_types,
    const int* __restrict__ op_before_pos,
    const int* __restrict__ op_after_pos,
    const int* __restrict__ n_ops,
    float* __restrict__ g_sums,
    int* __restrict__ g_cnts)
{
    __shared__ float s_sums[3];
    __shared__ int   s_cnts[3];
    if (threadIdx.x < 3) { s_sums[threadIdx.x] = 0.0f; s_cnts[threadIdx.x] = 0; }
    __syncthreads();

    const int wave = threadIdx.x >> 6;
    const int lane = threadIdx.x & 63;
    const int gid  = blockIdx.x * 4 + wave;      // [0, B*M)
    const int b    = gid >> 8;                   // M = 256
    const int m    = gid & (Mc - 1);

    const int n  = n_ops[b];
    const int t  = op_types[b * Mc + m];
    const int bp = op_before_pos[b * Mc + m];
    const int ap = op_after_pos[b * Mc + m];

    const bool in_n   = m < n;
    const bool pos_ok = (bp >= 0) & (bp < Lc) & (ap >= 0) & (ap < Lc);
    const bool valid  = in_n && pos_ok;

    const bool id_mask  = valid && (t == OP_IDENTITY);
    const bool col_mask = valid && (t == OP_STAR_ZERO);

    bool cancel_mask = false;
    int  apn_c = 0;
    if (valid && t == OP_CANCEL_START) {
        const int ot_next = (m + 1 < Mc) ? op_types[b * Mc + m + 1] : -1;
        const int ap_next = (m + 1 < Mc) ? op_after_pos[b * Mc + m + 1] : Lc;
        cancel_mask = ((m + 1) < n) && (ot_next == OP_CANCEL_END) && (ap_next < Lc);
        apn_c = min(max(ap_next, 0), Lc - 1);
    }

    if (id_mask || col_mask || cancel_mask) {
        const size_t baseB = (size_t)b * Lc * Dc;

        // before-row needed by every branch; pos_ok guarantees bp in range
        const float4* pbv = (const float4*)(states + baseB + (size_t)bp * Dc);
        const float4 bef0 = pbv[lane];
        const float4 bef1 = pbv[lane + 64];

        if (id_mask || col_mask) {
            const float4* pav = (const float4*)(states + baseB + (size_t)ap * Dc);
            const float4 aft0 = pav[lane];
            const float4 aft1 = pav[lane + 64];

            if (id_mask) {
                float acc = 0.0f, d;
                d = aft0.x - bef0.x; acc += d * d;
                d = aft0.y - bef0.y; acc += d * d;
                d = aft0.z - bef0.z; acc += d * d;
                d = aft0.w - bef0.w; acc += d * d;
                d = aft1.x - bef1.x; acc += d * d;
                d = aft1.y - bef1.y; acc += d * d;
                d = aft1.z - bef1.z; acc += d * d;
                d = aft1.w - bef1.w; acc += d * d;
                float mse = wave_allreduce_sum(acc) * (1.0f / (float)Dc);
                if (lane == 0) { atomicAdd(&s_sums[0], mse); atomicAdd(&s_cnts[0], 1); }
            } else {
                // collapse: relu(ent_after - ent_before + 0.5)
                float ea[8], eb[8];
                ea[0] = aft0.x * aft0.x; ea[1] = aft0.y * aft0.y;
                ea[2] = aft0.z * aft0.z; ea[3] = aft0.w * aft0.w;
                ea[4] = aft1.x * aft1.x; ea[5] = aft1.y * aft1.y;
                ea[6] = aft1.z * aft1.z; ea[7] = aft1.w * aft1.w;
                eb[0] = bef0.x * bef0.x; eb[1] = bef0.y * bef0.y;
                eb[2] = bef0.z * bef0.z; eb[3] = bef0.w * bef0.w;
                eb[4] = bef1.x * bef1.x; eb[5] = bef1.y * bef1.y;
                eb[6] = bef1.z * bef1.z; eb[7] = bef1.w * bef1.w;

                float Sa = 0.0f, Sb = 0.0f;
                #pragma unroll
                for (int i = 0; i < 8; ++i) { Sa += ea[i]; Sb += eb[i]; }
                Sa = wave_allreduce_sum(Sa);
                Sb = wave_allreduce_sum(Sb);

                const float inva = 1.0f / (Sa + EPSc);
                const float invb = 1.0f / (Sb + EPSc);
                float ha = 0.0f, hb = 0.0f;
                #pragma unroll
                for (int i = 0; i < 8; ++i) {
                    float pa = ea[i] * inva;
                    float pb = eb[i] * invb;
                    ha += pa * __log2f(pa + EPSc);
                    hb += pb * __log2f(pb + EPSc);
                }
                float ent_a = -wave_allreduce_sum(ha);
                float ent_b = -wave_allreduce_sum(hb);
                float term = fmaxf(ent_a - ent_b + 0.5f, 0.0f);
                if (lane == 0) { atomicAdd(&s_sums[2], term); atomicAdd(&s_cnts[2], 1); }
            }
        }

        if (cancel_mask) {
            const float4* pnv = (const float4*)(states + baseB + (size_t)apn_c * Dc);
            const float4 pr0 = pnv[lane];
            const float4 pr1 = pnv[lane + 64];
            float acc = 0.0f, d;
            d = pr0.x - bef0.x; acc += d * d;
            d = pr0.y - bef0.y; acc += d * d;
            d = pr0.z - bef0.z; acc += d * d;
            d = pr0.w - bef0.w; acc += d * d;
            d = pr1.x - bef1.x; acc += d * d;
            d = pr1.y - bef1.y; acc += d * d;
            d = pr1.z - bef1.z; acc += d * d;
            d = pr1.w - bef1.w; acc += d * d;
            float mse = wave_allreduce_sum(acc) * (1.0f / (float)Dc);
            if (lane == 0) { atomicAdd(&s_sums[1], mse); atomicAdd(&s_cnts[1], 1); }
        }
    }

    __syncthreads();
    if (threadIdx.x < 3) {
        if (s_cnts[threadIdx.x] > 0) {
            atomicAdd(&g_sums[threadIdx.x], s_sums[threadIdx.x]);
            atomicAdd(&g_cnts[threadIdx.x], s_cnts[threadIdx.x]);
        }
    }
}

__global__ void finalize_kernel(const float* __restrict__ g_sums,
                                const int* __restrict__ g_cnts,
                                float* __restrict__ out)
{
    if (threadIdx.x == 0 && blockIdx.x == 0) {
        float id = g_sums[0] / fmaxf((float)g_cnts[0], 1.0f);
        float ca = g_sums[1] / fmaxf((float)g_cnts[1], 1.0f);
        float co = g_sums[2] / fmaxf((float)g_cnts[2], 1.0f);
        out[0] = id + ca + 0.5f * co;   // IDENTITY_W=CANCEL_W=1, COLLAPSE_W=0.5
        out[1] = id;
        out[2] = ca;
        out[3] = co;
    }
}

extern "C" void kernel_launch(void* const* d_in, const int* in_sizes, int n_in,
                              void* d_out, int out_size, void* d_ws, size_t ws_size,
                              hipStream_t stream) {
    const float* states    = (const float*)d_in[0];
    const int*   op_types  = (const int*)d_in[1];
    const int*   op_before = (const int*)d_in[2];
    const int*   op_after  = (const int*)d_in[3];
    const int*   n_ops     = (const int*)d_in[4];
    float* out = (float*)d_out;

    float* g_sums = (float*)d_ws;
    int*   g_cnts = (int*)((char*)d_ws + 3 * sizeof(float));

    // d_ws is re-poisoned to 0xAA before every timed launch — zero the 24 B we use.
    hipMemsetAsync(d_ws, 0, 24, stream);

    // one wave per (b, m): B*M = 8192 waves, 4 waves/block -> 2048 blocks
    ops_kernel<<<(Bc * Mc) / 4, 256, 0, stream>>>(
        states, op_types, op_before, op_after, n_ops, g_sums, g_cnts);

    finalize_kernel<<<1, 64, 0, stream>>>(g_sums, g_cnts, out);
}